// Round 9
// baseline (430.335 us; speedup 1.0000x reference)
//
#include <hip/hip_runtime.h>
#include <cstdint>
#include <cstddef>

constexpr int H_DIM = 1024;
constexpr int NE    = 8;
constexpr int NT    = 16384;
constexpr int NP    = NT * 2;   // total (token, expert) pairs: exactly 2 per token

constexpr int BM = 128, BN = 128, BK = 32;
constexpr int NKT = H_DIM / BK;          // 32 K-tiles
constexpr int MAX_WG = (NP / BM + NE) * (H_DIM / BN);  // 2112

typedef __attribute__((ext_vector_type(8)))  short          short8;
typedef __attribute__((ext_vector_type(8)))  unsigned short ushort8;
typedef __attribute__((ext_vector_type(4)))  float          f32x4;

__device__ __forceinline__ unsigned short f2bf(float f) {
  union { float f; uint32_t u; } c; c.f = f;
  uint32_t u = c.u;
  u = (u + 0x7fffu + ((u >> 16) & 1u)) >> 16;   // RNE
  return (unsigned short)u;
}
__device__ __forceinline__ float bf2f(unsigned short h) {
  union { uint32_t u; float f; } c; c.u = ((uint32_t)h) << 16;
  return c.f;
}

// async 16B global -> LDS (wave-uniform LDS base; lane auto-offset *16; global addr per-lane)
__device__ __forceinline__ void gload16(const unsigned short* g, unsigned short* l) {
  __builtin_amdgcn_global_load_lds((const __attribute__((address_space(1))) void*)g,
                                   (__attribute__((address_space(3))) void*)l, 16, 0, 0);
}

// ---------------------------------------------------------------------------
// Fused prep: blocks [0,4096) = xgate (X->Xb bf16 + gating);
//             blocks [4096,8192) = W transpose-convert (fp32 [in,out] -> bf16 [out,in])
// ---------------------------------------------------------------------------
__global__ __launch_bounds__(256) void prep_kernel(
    const float* __restrict__ X, const float* __restrict__ Wg,
    const float* __restrict__ bg, unsigned short* __restrict__ Xb,
    float* __restrict__ gate_out, int* __restrict__ tk_e, float* __restrict__ tk_w,
    const float* __restrict__ W1, const float* __restrict__ W2,
    unsigned short* __restrict__ T1, unsigned short* __restrict__ T2)
{
  __shared__ float tile[64][65];
  int b = blockIdx.x;
  if (b >= 4096) {
    // ---- transpose-convert ----
    int t = b - 4096;
    int zi = t >> 8;                         // 0..15
    const float* W = (zi < 8) ? W1 : W2;
    unsigned short* T = (zi < 8) ? T1 : T2;
    int e  = zi & 7;
    int o0 = ((t >> 4) & 15) * 64;
    int h0 = (t & 15) * 64;
    int c  = threadIdx.x & 63;
    int r0 = (threadIdx.x >> 6) * 16;
    const float* src = W + ((size_t)e * H_DIM + h0) * H_DIM + o0;
#pragma unroll
    for (int i = 0; i < 16; ++i)
      tile[r0 + i][c] = src[(size_t)(r0 + i) * H_DIM + c];
    __syncthreads();
    unsigned short* dst = T + ((size_t)e * H_DIM + o0) * H_DIM + h0;
#pragma unroll
    for (int i = 0; i < 16; ++i)
      dst[(size_t)(r0 + i) * H_DIM + c] = f2bf(tile[c][r0 + i]);
    return;
  }

  // ---- xgate ----
  int wid = threadIdx.x >> 6, lane = threadIdx.x & 63;
  int n = b * 4 + wid;
  const float* xr = X + (size_t)n * H_DIM;

  const float4* xp = (const float4*)(xr + lane * 16);
  float4 f0 = xp[0], f1 = xp[1], f2 = xp[2], f3 = xp[3];
  float v[16] = {f0.x,f0.y,f0.z,f0.w, f1.x,f1.y,f1.z,f1.w,
                 f2.x,f2.y,f2.z,f2.w, f3.x,f3.y,f3.z,f3.w};

  ushort8 u0, u1;
#pragma unroll
  for (int j = 0; j < 8; ++j) { u0[j] = f2bf(v[j]); u1[j] = f2bf(v[8 + j]); }
  ushort8* xb = (ushort8*)(Xb + (size_t)n * H_DIM + lane * 16);
  xb[0] = u0; xb[1] = u1;

  float acc[8];
#pragma unroll
  for (int e = 0; e < 8; ++e) acc[e] = 0.f;
#pragma unroll
  for (int j = 0; j < 16; ++j) {
    int h = lane * 16 + j;
    const float4* wg = (const float4*)(Wg + (size_t)h * 8);
    float4 a = wg[0], bb = wg[1];
    float xv = v[j];
    acc[0] += xv * a.x;  acc[1] += xv * a.y;  acc[2] += xv * a.z;  acc[3] += xv * a.w;
    acc[4] += xv * bb.x; acc[5] += xv * bb.y; acc[6] += xv * bb.z; acc[7] += xv * bb.w;
  }
#pragma unroll
  for (int m = 1; m < 64; m <<= 1) {
#pragma unroll
    for (int e = 0; e < 8; ++e) acc[e] += __shfl_xor(acc[e], m);
  }
#pragma unroll
  for (int e = 0; e < 8; ++e) acc[e] += bg[e];

  float mx = acc[0];
#pragma unroll
  for (int e = 1; e < 8; ++e) mx = fmaxf(mx, acc[e]);
  float g[8], s = 0.f;
#pragma unroll
  for (int e = 0; e < 8; ++e) { g[e] = __expf(acc[e] - mx); s += g[e]; }
  float inv = 1.f / s;
#pragma unroll
  for (int e = 0; e < 8; ++e) g[e] *= inv;

  int e0 = 0; float b0 = g[0];
#pragma unroll
  for (int e = 1; e < 8; ++e) if (g[e] > b0) { b0 = g[e]; e0 = e; }
  int e1 = -1; float b1v = -1.f;
#pragma unroll
  for (int e = 0; e < 8; ++e) if (e != e0 && g[e] > b1v) { b1v = g[e]; e1 = e; }
  float s2 = b0 + b1v + 1e-9f;

  if (lane == 0) {
    float4* gp = (float4*)(gate_out + (size_t)n * 8);
    gp[0] = make_float4(g[0], g[1], g[2], g[3]);
    gp[1] = make_float4(g[4], g[5], g[6], g[7]);
    tk_e[2 * n] = e0; tk_e[2 * n + 1] = e1;
    tk_w[2 * n] = b0 / s2; tk_w[2 * n + 1] = b1v / s2;
  }
}

// ---------------------------------------------------------------------------
// Routing: block-hist -> scan+worklist -> block-place
// ---------------------------------------------------------------------------
__global__ __launch_bounds__(256) void hist_kernel(
    const int* __restrict__ tk_e, int* __restrict__ blockHist)
{
  __shared__ int h[8];
  if (threadIdx.x < 8) h[threadIdx.x] = 0;
  __syncthreads();
  int i0 = blockIdx.x * 512 + threadIdx.x;
  atomicAdd(&h[tk_e[i0]], 1);
  atomicAdd(&h[tk_e[i0 + 256]], 1);
  __syncthreads();
  if (threadIdx.x < 8) blockHist[blockIdx.x * 8 + threadIdx.x] = h[threadIdx.x];
}

// Worklist ordered (e, nt) outer, mt inner -> XCD chunking keeps one B col-panel
// (256 KB) L2-resident per XCD while mt-blocks stream past it.
__global__ void scan_worklist_kernel(const int* __restrict__ blockHist,
                                     int* __restrict__ blockBase,
                                     int* __restrict__ count, int* __restrict__ offs,
                                     int* __restrict__ wl, int* __restrict__ wlCount)
{
  __shared__ int nmt[8], ebase[8], totalS;
  int e = threadIdx.x;
  if (e < 8) {
    int run = 0;
    for (int b = 0; b < 64; ++b) { blockBase[b * 8 + e] = run; run += blockHist[b * 8 + e]; }
    count[e] = run;
  }
  __syncthreads();
  if (threadIdx.x == 0) {
    int o = 0, wo = 0;
    for (int k = 0; k < 8; ++k) {
      offs[k] = o; o += count[k];
      nmt[k] = (count[k] + BM - 1) / BM;
      ebase[k] = wo; wo += nmt[k] * (H_DIM / BN);
    }
    totalS = wo; wlCount[0] = wo;
  }
  __syncthreads();
  if (e < 8) {
    int o = offs[e];
    for (int b = 0; b < 64; ++b) blockBase[b * 8 + e] += o;
  }
  int total = totalS;
  for (int i = threadIdx.x; i < total; i += blockDim.x) {
    int ee = 0;
    while (ee < 7 && i >= ebase[ee + 1]) ++ee;
    int loc = i - ebase[ee];
    int nt = loc / nmt[ee];
    int mt = loc - nt * nmt[ee];
    wl[i] = (ee << 20) | (nt << 16) | mt;
  }
}

__global__ __launch_bounds__(256) void place_kernel(
    const int* __restrict__ tk_e, const int* __restrict__ blockBase,
    int* __restrict__ pairTok, int* __restrict__ pairExp, int* __restrict__ slots)
{
  __shared__ int cur[8];
  if (threadIdx.x < 8) cur[threadIdx.x] = blockBase[blockIdx.x * 8 + threadIdx.x];
  __syncthreads();
#pragma unroll
  for (int j = 0; j < 2; ++j) {
    int i = blockIdx.x * 512 + j * 256 + threadIdx.x;
    int e = tk_e[i];
    int s = atomicAdd(&cur[e], 1);
    pairTok[s] = i >> 1; pairExp[s] = e; slots[i] = s;
  }
}

// ---------------------------------------------------------------------------
// 128x128xBK32 MFMA GEMM, 4 waves (2x2 of 64x64), 16x16x32 frags,
// 4-slot LDS ring (32 KB -> 3 blocks/CU), prefetch depth 3, counted vmcnt(8),
// one barrier per K-tile. Static XCD-chunked worklist (R5-verified: 121 us,
// 0 bank conflicts). st_16x32 swizzle via pre-permuted global source + XOR'd
// ds_read.
// ---------------------------------------------------------------------------
template<bool GATHER>
__global__ __launch_bounds__(256, 3) void gemm4d_kernel(
    const unsigned short* __restrict__ Ab,   // GATHER: Xb [NT][H]; else buf rows [NP][H]
    const unsigned short* __restrict__ Bt,   // [E][H(out)][H(in)] bf16
    const float* __restrict__ bias,          // [E][H]
    const int* __restrict__ pairTok,
    const int* __restrict__ count, const int* __restrict__ offs,
    const int* __restrict__ wl, const int* __restrict__ wlCount,
    unsigned short* __restrict__ Out)        // [NP][H] bf16
{
  __shared__ unsigned short As[4 * 4096];   // 32 KB: 4 slots x (128 rows x 32 k)
  __shared__ unsigned short Bs[4 * 4096];   // 32 KB

  const int total = wlCount[0];
  const int orig = blockIdx.x;
  if (orig >= total) return;
  // bijective XCD chunking (m204)
  const int qq = total >> 3, rr = total & 7;
  const int xcd = orig & 7, sub = orig >> 3;
  const int idx = (xcd < rr ? xcd * (qq + 1) : rr * (qq + 1) + (xcd - rr) * qq) + sub;
  const int ent = wl[idx];
  const int e = ent >> 20, ntb = (ent >> 16) & 15, mtb = ent & 0xffff;
  const int cnt = count[e], base = offs[e];

  const int tid = threadIdx.x;
  const int wid = tid >> 6, l = tid & 63;
  const int wr = wid >> 1, wc = wid & 1;

  // ---- staging source geometry (R5-verified) ----
  const int rsub = (l >> 2);
  const int kswz = ((l & 3) * 8) ^ (((l >> 5) & 1) << 4);

  const unsigned short *apg0, *apg1, *bpg0, *bpg1;
  {
    int r0 = wid * 16 + rsub;          // issue 0 rows [0,64)
    int r1 = 64 + wid * 16 + rsub;     // issue 1 rows [64,128)
    int g0 = mtb * BM + r0; if (g0 >= cnt) g0 = cnt - 1;
    int g1 = mtb * BM + r1; if (g1 >= cnt) g1 = cnt - 1;
    size_t a0, a1;
    if (GATHER) { a0 = (size_t)pairTok[base + g0]; a1 = (size_t)pairTok[base + g1]; }
    else        { a0 = (size_t)(base + g0);        a1 = (size_t)(base + g1); }
    apg0 = Ab + a0 * H_DIM + kswz;
    apg1 = Ab + a1 * H_DIM + kswz;
    const unsigned short* bb = Bt + ((size_t)e * H_DIM + ntb * BN) * H_DIM + kswz;
    bpg0 = bb + (size_t)r0 * H_DIM;
    bpg1 = bb + (size_t)r1 * H_DIM;
  }

  // frag-read byte offset within 1KB subtile, same XOR involution
  const int loff = ((l & 15) * 64 + (l >> 4) * 16) ^ (((l >> 3) & 1) << 5);

  auto STAGE = [&](int u, int slot) {
    unsigned short* ad = As + slot * 4096 + wid * 512;
    unsigned short* bd = Bs + slot * 4096 + wid * 512;
    gload16(apg0 + (size_t)u * BK, ad);
    gload16(apg1 + (size_t)u * BK, ad + 2048);
    gload16(bpg0 + (size_t)u * BK, bd);
    gload16(bpg1 + (size_t)u * BK, bd + 2048);
  };

  // ---- prologue: stage tiles 0..2 (depth 3); ensure tile 0 done ----
  STAGE(0, 0); STAGE(1, 1); STAGE(2, 2);
  asm volatile("s_waitcnt vmcnt(8)" ::: "memory");
  __builtin_amdgcn_s_barrier();

  f32x4 acc[4][4] = {};

#pragma unroll 4
  for (int t = 0; t < NKT; ++t) {
    const int sl = t & 3;
    const char* aB = (const char*)As + sl * 8192 + wr * 4096 + loff;
    const char* bB = (const char*)Bs + sl * 8192 + wc * 4096 + loff;

    short8 af[4], bfr[4];
#pragma unroll
    for (int j = 0; j < 4; ++j) af[j] = *(const short8*)(aB + j * 1024);
#pragma unroll
    for (int r = 0; r < 4; ++r) bfr[r] = *(const short8*)(bB + r * 1024);

    if (t + 3 < NKT) STAGE(t + 3, (t + 3) & 3);

    __builtin_amdgcn_s_setprio(1);
#pragma unroll
    for (int j = 0; j < 4; ++j)
#pragma unroll
      for (int r = 0; r < 4; ++r)
        acc[j][r] = __builtin_amdgcn_mfma_f32_16x16x32_bf16(af[j], bfr[r], acc[j][r], 0, 0, 0);
    __builtin_amdgcn_s_setprio(0);

    if (t + 3 < NKT)       asm volatile("s_waitcnt vmcnt(8)" ::: "memory");
    else if (t + 3 == NKT) asm volatile("s_waitcnt vmcnt(4)" ::: "memory");
    else if (t + 2 == NKT) asm volatile("s_waitcnt vmcnt(0)" ::: "memory");
    __builtin_amdgcn_s_barrier();
  }

  // ---- epilogue: + bias, write bf16 ----
  float bvv[4];
#pragma unroll
  for (int r = 0; r < 4; ++r)
    bvv[r] = bias[e * H_DIM + ntb * BN + wc * 64 + r * 16 + (l & 15)];
#pragma unroll
  for (int j = 0; j < 4; ++j) {
    int grow0 = mtb * BM + wr * 64 + j * 16 + (l >> 4) * 4;
#pragma unroll
    for (int r = 0; r < 4; ++r) {
      int gcol = ntb * BN + wc * 64 + r * 16 + (l & 15);
#pragma unroll
      for (int v = 0; v < 4; ++v) {
        int row = grow0 + v;
        if (row < cnt)
          Out[(size_t)(base + row) * H_DIM + gcol] = f2bf(acc[j][r][v] + bvv[r]);
      }
    }
  }
}

// ---------------------------------------------------------------------------
// In-place relu(LayerNorm(row)) on bf16 rows; one wave per row.
// ---------------------------------------------------------------------------
__global__ __launch_bounds__(256) void ln_relu_kernel(
    unsigned short* __restrict__ buf, const float* __restrict__ gamma,
    const float* __restrict__ beta, const int* __restrict__ pairExp)
{
  int wid = threadIdx.x >> 6, lane = threadIdx.x & 63;
  int row = blockIdx.x * 4 + wid;
  int e = pairExp[row];
  unsigned short* r = buf + (size_t)row * H_DIM;
  ushort8 u0 = ((const ushort8*)r)[lane];
  ushort8 u1 = ((const ushort8*)r)[lane + 64];
  float v[16];
#pragma unroll
  for (int j = 0; j < 8; ++j) { v[j] = bf2f(u0[j]); v[8 + j] = bf2f(u1[j]); }
  float s = 0.f, ss = 0.f;
#pragma unroll
  for (int j = 0; j < 16; ++j) { s += v[j]; ss += v[j] * v[j]; }
#pragma unroll
  for (int m = 1; m < 64; m <<= 1) { s += __shfl_xor(s, m); ss += __shfl_xor(ss, m); }
  float mean = s * (1.f / 1024.f);
  float var  = ss * (1.f / 1024.f) - mean * mean;
  float rs   = rsqrtf(var + 1e-5f);

  int h0 = lane * 8, h1 = 512 + lane * 8;
  const float4* gp0 = (const float4*)(gamma + (size_t)e * H_DIM + h0);
  const float4* bp0 = (const float4*)(beta  + (size_t)e * H_DIM + h0);
  const float4* gp1 = (const float4*)(gamma + (size_t)e * H_DIM + h1);
  const float4* bp1 = (const float4*)(beta  + (size_t)e * H_DIM + h1);
  float4 ga = gp0[0], gb = gp0[1], gc = gp1[0], gd = gp1[1];
  float4 ba = bp0[0], bb = bp0[1], bc = bp1[0], bd = bp1[1];
  float gv[16] = {ga.x,ga.y,ga.z,ga.w, gb.x,gb.y,gb.z,gb.w,
                  gc.x,gc.y,gc.z,gc.w, gd.x,gd.y,gd.z,gd.w};
  float bv[16] = {ba.x,ba.y,ba.z,ba.w, bb.x,bb.y,bb.z,bb.w,
                  bc.x,bc.y,bc.z,bc.w, bd.x,bd.y,bd.z,bd.w};
#pragma unroll
  for (int j = 0; j < 8; ++j) {
    float t0 = fmaxf((v[j]     - mean) * rs * gv[j]     + bv[j],     0.f);
    float t1 = fmaxf((v[8 + j] - mean) * rs * gv[8 + j] + bv[8 + j], 0.f);
    u0[j] = f2bf(t0); u1[j] = f2bf(t1);
  }
  ((ushort8*)r)[lane] = u0; ((ushort8*)r)[lane + 64] = u1;
}

// ---------------------------------------------------------------------------
// Combine: per token, LN2 each of its 2 expert rows, y=relu(x+u), out = sum w*y
// ---------------------------------------------------------------------------
__global__ __launch_bounds__(256) void combine_kernel(
    const unsigned short* __restrict__ buf2, const float* __restrict__ X,
    const float* __restrict__ g2, const float* __restrict__ be2,
    const int* __restrict__ slots, const int* __restrict__ tk_e,
    const float* __restrict__ tk_w, float* __restrict__ out)
{
  int wid = threadIdx.x >> 6, lane = threadIdx.x & 63;
  int n = blockIdx.x * 4 + wid;
  int h0 = lane * 8, h1 = 512 + lane * 8;

  const float4* xp0 = (const float4*)(X + (size_t)n * H_DIM + h0);
  const float4* xp1 = (const float4*)(X + (size_t)n * H_DIM + h1);
  float4 xa = xp0[0], xb = xp0[1], xc = xp1[0], xd = xp1[1];
  float xv[16] = {xa.x,xa.y,xa.z,xa.w, xb.x,xb.y,xb.z,xb.w,
                  xc.x,xc.y,xc.z,xc.w, xd.x,xd.y,xd.z,xd.w};
  float o[16];
#pragma unroll
  for (int j = 0; j < 16; ++j) o[j] = 0.f;

#pragma unroll
  for (int k = 0; k < 2; ++k) {
    int slot = slots[2 * n + k];
    int e = tk_e[2 * n + k];
    float w = tk_w[2 * n + k];
    const unsigned short* r = buf2 + (size_t)slot * H_DIM;
    ushort8 u0 = ((const ushort8*)r)[lane];
    ushort8 u1 = ((const ushort8*)r)[lane + 64];
    float v[16];
#pragma unroll
    for (int j = 0; j < 8; ++j) { v[j] = bf2f(u0[j]); v[8 + j] = bf2f(u1[j]); }
    float s = 0.f, ss = 0.f;
#pragma unroll
    for (int j = 0; j < 16; ++j) { s += v[j]; ss += v[j] * v[j]; }
#pragma unroll
    for (int m = 1; m < 64; m <<= 1) { s += __shfl_xor(s, m); ss += __shfl_xor(ss, m); }
    float mean = s * (1.f / 1024.f);
    float var  = ss * (1.f / 1024.f) - mean * mean;
    float rs   = rsqrtf(var + 1e-5f);

    const float4* gp0 = (const float4*)(g2  + (size_t)e * H_DIM + h0);
    const float4* bp0 = (const float4*)(be2 + (size_t)e * H_DIM + h0);
    const float4* gp1 = (const float4*)(g2  + (size_t)e * H_DIM + h1);
    const float4* bp1 = (const float4*)(be2 + (size_t)e * H_DIM + h1);
    float4 ga = gp0[0], gb = gp0[1], gc = gp1[0], gd = gp1[1];
    float4 ba = bp0[0], bb = bp0[1], bc = bp1[0], bd = bp1[1];
    float gv[16] = {ga.x,ga.y,ga.z,ga.w, gb.x,gb.y,gb.z,gb.w,
                    gc.x,gc.y,gc.z,gc.w, gd.x,gd.y,gd.z,gd.w};
    float bvv[16] = {ba.x,ba.y,ba.z,ba.w, bb.x,bb.y,bb.z,bb.w,
                     bc.x,bc.y,bc.z,bc.w, bd.x,bd.y,bd.z,bd.w};
#pragma unroll
    for (int j = 0; j < 16; ++j) {
      float u = (v[j] - mean) * rs * gv[j] + bvv[j];
      float y = fmaxf(xv[j] + u, 0.f);
      o[j] += w * y;
    }
  }

  float4* op0 = (float4*)(out + (size_t)n * H_DIM + h0);
  float4* op1 = (float4*)(out + (size_t)n * H_DIM + h1);
  op0[0] = make_float4(o[0], o[1], o[2], o[3]);
  op0[1] = make_float4(o[4], o[5], o[6], o[7]);
  op1[0] = make_float4(o[8], o[9], o[10], o[11]);
  op1[1] = make_float4(o[12], o[13], o[14], o[15]);
}

// ---------------------------------------------------------------------------
extern "C" void kernel_launch(void* const* d_in, const int* in_sizes, int n_in,
                              void* d_out, int out_size, void* d_ws, size_t ws_size,
                              hipStream_t stream)
{
  const float* x   = (const float*)d_in[0];
  const float* Wg  = (const float*)d_in[1];
  const float* bg  = (const float*)d_in[2];
  const float* W1  = (const float*)d_in[3];
  const float* b1  = (const float*)d_in[4];
  const float* g1  = (const float*)d_in[5];
  const float* be1 = (const float*)d_in[6];
  const float* W2  = (const float*)d_in[7];
  const float* b2  = (const float*)d_in[8];
  const float* g2  = (const float*)d_in[9];
  const float* be2 = (const float*)d_in[10];
  float* out = (float*)d_out;
  float* gate_out = out + (size_t)NT * H_DIM;

  char* ws = (char*)d_ws;
  size_t off = 0;
  auto alloc = [&](size_t bytes) { char* p = ws + off; off += (bytes + 255) & ~(size_t)255; return p; };
  unsigned short* w1bt = (unsigned short*)alloc((size_t)NE * H_DIM * H_DIM * 2);
  unsigned short* w2bt = (unsigned short*)alloc((size_t)NE * H_DIM * H_DIM * 2);
  unsigned short* buf1 = (unsigned short*)alloc((size_t)NP * H_DIM * 2);
  unsigned short* buf2 = (unsigned short*)alloc((size_t)NP * H_DIM * 2);
  int*   tk_e      = (int*)alloc((size_t)NP * 4);
  float* tk_w      = (float*)alloc((size_t)NP * 4);
  int*   pairTok   = (int*)alloc((size_t)NP * 4);
  int*   pairExp   = (int*)alloc((size_t)NP * 4);
  int*   slots     = (int*)alloc((size_t)NP * 4);
  int*   blockHist = (int*)alloc(64 * 8 * 4);
  int*   blockBase = (int*)alloc(64 * 8 * 4);
  int*   count     = (int*)alloc(8 * 4);
  int*   offs      = (int*)alloc(8 * 4);
  int*   wl        = (int*)alloc(MAX_WG * 4);
  int*   wlCount   = (int*)alloc(4);
  (void)in_sizes; (void)n_in; (void)out_size; (void)ws_size;

  // Xb (bf16 copy of X) aliases buf2: consumed by gemm1 before gemm2 writes buf2.
  unsigned short* Xb = buf2;

  prep_kernel<<<dim3(8192), 256, 0, stream>>>(
      x, Wg, bg, Xb, gate_out, tk_e, tk_w, W1, W2, w1bt, w2bt);
  hist_kernel<<<dim3(64), 256, 0, stream>>>(tk_e, blockHist);
  scan_worklist_kernel<<<dim3(1), 256, 0, stream>>>(
      blockHist, blockBase, count, offs, wl, wlCount);
  place_kernel<<<dim3(64), 256, 0, stream>>>(tk_e, blockBase, pairTok, pairExp, slots);
  gemm4d_kernel<true><<<dim3(MAX_WG), 256, 0, stream>>>(
      Xb, w1bt, b1, pairTok, count, offs, wl, wlCount, buf1);
  ln_relu_kernel<<<dim3(NP / 4), 256, 0, stream>>>(buf1, g1, be1, pairExp);
  gemm4d_kernel<false><<<dim3(MAX_WG), 256, 0, stream>>>(
      buf1, w2bt, b2, pairTok, count, offs, wl, wlCount, buf2);
  combine_kernel<<<dim3(NT / 4), 256, 0, stream>>>(
      buf2, x, g2, be2, slots, tk_e, tk_w, out);
}

// Round 10
// 414.194 us; speedup vs baseline: 1.0390x; 1.0390x over previous
//
#include <hip/hip_runtime.h>
#include <cstdint>
#include <cstddef>

constexpr int H_DIM = 1024;
constexpr int NE    = 8;
constexpr int NT    = 16384;
constexpr int NP    = NT * 2;   // total (token, expert) pairs: exactly 2 per token

constexpr int BM = 256, BN = 128, BK = 32;
constexpr int NKT = H_DIM / BK;          // 32 K-tiles
constexpr int MAX_WG = (NP / BM + NE) * (H_DIM / BN);  // (128+8)*8 = 1088

typedef __attribute__((ext_vector_type(8)))  short          short8;
typedef __attribute__((ext_vector_type(8)))  unsigned short ushort8;
typedef __attribute__((ext_vector_type(4)))  float          f32x4;

__device__ __forceinline__ unsigned short f2bf(float f) {
  union { float f; uint32_t u; } c; c.f = f;
  uint32_t u = c.u;
  u = (u + 0x7fffu + ((u >> 16) & 1u)) >> 16;   // RNE
  return (unsigned short)u;
}
__device__ __forceinline__ float bf2f(unsigned short h) {
  union { uint32_t u; float f; } c; c.u = ((uint32_t)h) << 16;
  return c.f;
}

// async 16B global -> LDS (wave-uniform LDS base; lane auto-offset *16; global addr per-lane)
__device__ __forceinline__ void gload16(const unsigned short* g, unsigned short* l) {
  __builtin_amdgcn_global_load_lds((const __attribute__((address_space(1))) void*)g,
                                   (__attribute__((address_space(3))) void*)l, 16, 0, 0);
}

// ---------------------------------------------------------------------------
// Fused prep: blocks [0,4096) = xgate (X->Xb bf16 + gating);
//             blocks [4096,8192) = W transpose-convert (fp32 [in,out] -> bf16 [out,in])
// ---------------------------------------------------------------------------
__global__ __launch_bounds__(256) void prep_kernel(
    const float* __restrict__ X, const float* __restrict__ Wg,
    const float* __restrict__ bg, unsigned short* __restrict__ Xb,
    float* __restrict__ gate_out, int* __restrict__ tk_e, float* __restrict__ tk_w,
    const float* __restrict__ W1, const float* __restrict__ W2,
    unsigned short* __restrict__ T1, unsigned short* __restrict__ T2)
{
  __shared__ float tile[64][65];
  int b = blockIdx.x;
  if (b >= 4096) {
    // ---- transpose-convert ----
    int t = b - 4096;
    int zi = t >> 8;                         // 0..15
    const float* W = (zi < 8) ? W1 : W2;
    unsigned short* T = (zi < 8) ? T1 : T2;
    int e  = zi & 7;
    int o0 = ((t >> 4) & 15) * 64;
    int h0 = (t & 15) * 64;
    int c  = threadIdx.x & 63;
    int r0 = (threadIdx.x >> 6) * 16;
    const float* src = W + ((size_t)e * H_DIM + h0) * H_DIM + o0;
#pragma unroll
    for (int i = 0; i < 16; ++i)
      tile[r0 + i][c] = src[(size_t)(r0 + i) * H_DIM + c];
    __syncthreads();
    unsigned short* dst = T + ((size_t)e * H_DIM + o0) * H_DIM + h0;
#pragma unroll
    for (int i = 0; i < 16; ++i)
      dst[(size_t)(r0 + i) * H_DIM + c] = f2bf(tile[c][r0 + i]);
    return;
  }

  // ---- xgate ----
  int wid = threadIdx.x >> 6, lane = threadIdx.x & 63;
  int n = b * 4 + wid;
  const float* xr = X + (size_t)n * H_DIM;

  const float4* xp = (const float4*)(xr + lane * 16);
  float4 f0 = xp[0], f1 = xp[1], f2 = xp[2], f3 = xp[3];
  float v[16] = {f0.x,f0.y,f0.z,f0.w, f1.x,f1.y,f1.z,f1.w,
                 f2.x,f2.y,f2.z,f2.w, f3.x,f3.y,f3.z,f3.w};

  ushort8 u0, u1;
#pragma unroll
  for (int j = 0; j < 8; ++j) { u0[j] = f2bf(v[j]); u1[j] = f2bf(v[8 + j]); }
  ushort8* xb = (ushort8*)(Xb + (size_t)n * H_DIM + lane * 16);
  xb[0] = u0; xb[1] = u1;

  float acc[8];
#pragma unroll
  for (int e = 0; e < 8; ++e) acc[e] = 0.f;
#pragma unroll
  for (int j = 0; j < 16; ++j) {
    int h = lane * 16 + j;
    const float4* wg = (const float4*)(Wg + (size_t)h * 8);
    float4 a = wg[0], bb = wg[1];
    float xv = v[j];
    acc[0] += xv * a.x;  acc[1] += xv * a.y;  acc[2] += xv * a.z;  acc[3] += xv * a.w;
    acc[4] += xv * bb.x; acc[5] += xv * bb.y; acc[6] += xv * bb.z; acc[7] += xv * bb.w;
  }
#pragma unroll
  for (int m = 1; m < 64; m <<= 1) {
#pragma unroll
    for (int e = 0; e < 8; ++e) acc[e] += __shfl_xor(acc[e], m);
  }
#pragma unroll
  for (int e = 0; e < 8; ++e) acc[e] += bg[e];

  float mx = acc[0];
#pragma unroll
  for (int e = 1; e < 8; ++e) mx = fmaxf(mx, acc[e]);
  float g[8], s = 0.f;
#pragma unroll
  for (int e = 0; e < 8; ++e) { g[e] = __expf(acc[e] - mx); s += g[e]; }
  float inv = 1.f / s;
#pragma unroll
  for (int e = 0; e < 8; ++e) g[e] *= inv;

  int e0 = 0; float b0 = g[0];
#pragma unroll
  for (int e = 1; e < 8; ++e) if (g[e] > b0) { b0 = g[e]; e0 = e; }
  int e1 = -1; float b1v = -1.f;
#pragma unroll
  for (int e = 0; e < 8; ++e) if (e != e0 && g[e] > b1v) { b1v = g[e]; e1 = e; }
  float s2 = b0 + b1v + 1e-9f;

  if (lane == 0) {
    float4* gp = (float4*)(gate_out + (size_t)n * 8);
    gp[0] = make_float4(g[0], g[1], g[2], g[3]);
    gp[1] = make_float4(g[4], g[5], g[6], g[7]);
    tk_e[2 * n] = e0; tk_e[2 * n + 1] = e1;
    tk_w[2 * n] = b0 / s2; tk_w[2 * n + 1] = b1v / s2;
  }
}

// ---------------------------------------------------------------------------
// Routing: block-hist -> scan+worklist -> block-place
// ---------------------------------------------------------------------------
__global__ __launch_bounds__(256) void hist_kernel(
    const int* __restrict__ tk_e, int* __restrict__ blockHist)
{
  __shared__ int h[8];
  if (threadIdx.x < 8) h[threadIdx.x] = 0;
  __syncthreads();
  int i0 = blockIdx.x * 512 + threadIdx.x;
  atomicAdd(&h[tk_e[i0]], 1);
  atomicAdd(&h[tk_e[i0 + 256]], 1);
  __syncthreads();
  if (threadIdx.x < 8) blockHist[blockIdx.x * 8 + threadIdx.x] = h[threadIdx.x];
}

// Worklist ordered (e, nt) outer, mt inner -> XCD chunking keeps one B col-panel
// (256 KB) L2-resident per XCD while mt-blocks stream past it.
__global__ void scan_worklist_kernel(const int* __restrict__ blockHist,
                                     int* __restrict__ blockBase,
                                     int* __restrict__ count, int* __restrict__ offs,
                                     int* __restrict__ wl, int* __restrict__ wlCount)
{
  __shared__ int nmt[8], ebase[8], totalS;
  int e = threadIdx.x;
  if (e < 8) {
    int run = 0;
    for (int b = 0; b < 64; ++b) { blockBase[b * 8 + e] = run; run += blockHist[b * 8 + e]; }
    count[e] = run;
  }
  __syncthreads();
  if (threadIdx.x == 0) {
    int o = 0, wo = 0;
    for (int k = 0; k < 8; ++k) {
      offs[k] = o; o += count[k];
      nmt[k] = (count[k] + BM - 1) / BM;
      ebase[k] = wo; wo += nmt[k] * (H_DIM / BN);
    }
    totalS = wo; wlCount[0] = wo;
  }
  __syncthreads();
  if (e < 8) {
    int o = offs[e];
    for (int b = 0; b < 64; ++b) blockBase[b * 8 + e] += o;
  }
  int total = totalS;
  for (int i = threadIdx.x; i < total; i += blockDim.x) {
    int ee = 0;
    while (ee < 7 && i >= ebase[ee + 1]) ++ee;
    int loc = i - ebase[ee];
    int nt = loc / nmt[ee];
    int mt = loc - nt * nmt[ee];
    wl[i] = (ee << 20) | (nt << 16) | mt;
  }
}

__global__ __launch_bounds__(256) void place_kernel(
    const int* __restrict__ tk_e, const int* __restrict__ blockBase,
    int* __restrict__ pairTok, int* __restrict__ pairExp, int* __restrict__ slots)
{
  __shared__ int cur[8];
  if (threadIdx.x < 8) cur[threadIdx.x] = blockBase[blockIdx.x * 8 + threadIdx.x];
  __syncthreads();
#pragma unroll
  for (int j = 0; j < 2; ++j) {
    int i = blockIdx.x * 512 + j * 256 + threadIdx.x;
    int e = tk_e[i];
    int s = atomicAdd(&cur[e], 1);
    pairTok[s] = i >> 1; pairExp[s] = e; slots[i] = s;
  }
}

// ---------------------------------------------------------------------------
// 256x128xBK32 MFMA GEMM, 4 waves each owning a 64x128 wave-tile (4 A-frags x
// 8 B-frags = 42.7 FLOP/LDS-byte vs 32 before -- the LDS-BW fix). Ring-3
// (72 KB -> 2 blocks/CU), counted vmcnt(6), one barrier per K-tile. st_16x32
// swizzle via pre-permuted global source + XOR'd ds_read (verified 0-conflict).
// ---------------------------------------------------------------------------
template<bool GATHER>
__global__ __launch_bounds__(256, 2) void gemmw_kernel(
    const unsigned short* __restrict__ Ab,   // GATHER: Xb [NT][H]; else buf rows [NP][H]
    const unsigned short* __restrict__ Bt,   // [E][H(out)][H(in)] bf16
    const float* __restrict__ bias,          // [E][H]
    const int* __restrict__ pairTok,
    const int* __restrict__ count, const int* __restrict__ offs,
    const int* __restrict__ wl, const int* __restrict__ wlCount,
    unsigned short* __restrict__ Out)        // [NP][H] bf16
{
  __shared__ unsigned short As[3 * 8192];   // 48 KB: 3 slots x (256 rows x 32 k)
  __shared__ unsigned short Bs[3 * 4096];   // 24 KB: 3 slots x (128 cols x 32 k)

  const int total = wlCount[0];
  const int orig = blockIdx.x;
  if (orig >= total) return;
  // bijective XCD chunking (m204)
  const int qq = total >> 3, rr = total & 7;
  const int xcd = orig & 7, sub = orig >> 3;
  const int idx = (xcd < rr ? xcd * (qq + 1) : rr * (qq + 1) + (xcd - rr) * qq) + sub;
  const int ent = wl[idx];
  const int e = ent >> 20, ntb = (ent >> 16) & 15, mtb = ent & 0xffff;
  const int cnt = count[e], base = offs[e];

  const int tid = threadIdx.x;
  const int wid = tid >> 6, l = tid & 63;

  // ---- staging source geometry (R5-verified involution) ----
  const int rsub = (l >> 2);
  const int kswz = ((l & 3) * 8) ^ (((l >> 5) & 1) << 4);

  // A: 4 issues, subtile s = j*4 + wid (rows s*16..s*16+15)
  const unsigned short* apg[4];
#pragma unroll
  for (int j = 0; j < 4; ++j) {
    int g = mtb * BM + (j * 4 + wid) * 16 + rsub;
    if (g >= cnt) g = cnt - 1;
    size_t arow = GATHER ? (size_t)pairTok[base + g] : (size_t)(base + g);
    apg[j] = Ab + arow * H_DIM + kswz;
  }
  // B: 2 issues, subtile s = j*4 + wid (cols s*16..s*16+15)
  const unsigned short* bpg[2];
#pragma unroll
  for (int j = 0; j < 2; ++j) {
    int col = ntb * BN + (j * 4 + wid) * 16 + rsub;
    bpg[j] = Bt + ((size_t)e * H_DIM + col) * H_DIM + kswz;
  }

  // frag-read byte offset within 1KB subtile, same XOR involution
  const int loff = ((l & 15) * 64 + (l >> 4) * 16) ^ (((l >> 3) & 1) << 5);

  auto STAGE = [&](int u, int slot) {
    unsigned short* ad = As + slot * 8192 + wid * 512;
    unsigned short* bd = Bs + slot * 4096 + wid * 512;
#pragma unroll
    for (int j = 0; j < 4; ++j)
      gload16(apg[j] + (size_t)u * BK, ad + j * 2048);
#pragma unroll
    for (int j = 0; j < 2; ++j)
      gload16(bpg[j] + (size_t)u * BK, bd + j * 2048);
  };

  // ---- prologue: stage tiles 0,1 (6 loads/wave each); ensure tile 0 done ----
  STAGE(0, 0); STAGE(1, 1);
  asm volatile("s_waitcnt vmcnt(6)" ::: "memory");
  __builtin_amdgcn_s_barrier();

  f32x4 acc[4][8] = {};

  int sl = 0, sstage = 2;
  for (int t = 0; t < NKT; ++t) {
    const char* aB = (const char*)As + sl * 16384 + wid * 4096 + loff;
    const char* bB = (const char*)Bs + sl * 8192 + loff;

    short8 af[4], bfr[8];
#pragma unroll
    for (int j = 0; j < 4; ++j) af[j] = *(const short8*)(aB + j * 1024);
#pragma unroll
    for (int r = 0; r < 8; ++r) bfr[r] = *(const short8*)(bB + r * 1024);

    if (t + 2 < NKT) STAGE(t + 2, sstage);

    __builtin_amdgcn_s_setprio(1);
#pragma unroll
    for (int j = 0; j < 4; ++j)
#pragma unroll
      for (int r = 0; r < 8; ++r)
        acc[j][r] = __builtin_amdgcn_mfma_f32_16x16x32_bf16(af[j], bfr[r], acc[j][r], 0, 0, 0);
    __builtin_amdgcn_s_setprio(0);

    if (t + 2 < NKT)       asm volatile("s_waitcnt vmcnt(6)" ::: "memory");
    else if (t + 2 == NKT) asm volatile("s_waitcnt vmcnt(0)" ::: "memory");
    __builtin_amdgcn_s_barrier();

    sl = (sl == 2) ? 0 : sl + 1;
    sstage = (sstage == 2) ? 0 : sstage + 1;
  }

  // ---- epilogue: + bias, write bf16 ----
  float bvv[8];
#pragma unroll
  for (int r = 0; r < 8; ++r)
    bvv[r] = bias[e * H_DIM + ntb * BN + r * 16 + (l & 15)];
#pragma unroll
  for (int j = 0; j < 4; ++j) {
    int grow0 = mtb * BM + wid * 64 + j * 16 + (l >> 4) * 4;
#pragma unroll
    for (int r = 0; r < 8; ++r) {
      int gcol = ntb * BN + r * 16 + (l & 15);
#pragma unroll
      for (int v = 0; v < 4; ++v) {
        int row = grow0 + v;
        if (row < cnt)
          Out[(size_t)(base + row) * H_DIM + gcol] = f2bf(acc[j][r][v] + bvv[r]);
      }
    }
  }
}

// ---------------------------------------------------------------------------
// In-place relu(LayerNorm(row)) on bf16 rows; one wave per row.
// ---------------------------------------------------------------------------
__global__ __launch_bounds__(256) void ln_relu_kernel(
    unsigned short* __restrict__ buf, const float* __restrict__ gamma,
    const float* __restrict__ beta, const int* __restrict__ pairExp)
{
  int wid = threadIdx.x >> 6, lane = threadIdx.x & 63;
  int row = blockIdx.x * 4 + wid;
  int e = pairExp[row];
  unsigned short* r = buf + (size_t)row * H_DIM;
  ushort8 u0 = ((const ushort8*)r)[lane];
  ushort8 u1 = ((const ushort8*)r)[lane + 64];
  float v[16];
#pragma unroll
  for (int j = 0; j < 8; ++j) { v[j] = bf2f(u0[j]); v[8 + j] = bf2f(u1[j]); }
  float s = 0.f, ss = 0.f;
#pragma unroll
  for (int j = 0; j < 16; ++j) { s += v[j]; ss += v[j] * v[j]; }
#pragma unroll
  for (int m = 1; m < 64; m <<= 1) { s += __shfl_xor(s, m); ss += __shfl_xor(ss, m); }
  float mean = s * (1.f / 1024.f);
  float var  = ss * (1.f / 1024.f) - mean * mean;
  float rs   = rsqrtf(var + 1e-5f);

  int h0 = lane * 8, h1 = 512 + lane * 8;
  const float4* gp0 = (const float4*)(gamma + (size_t)e * H_DIM + h0);
  const float4* bp0 = (const float4*)(beta  + (size_t)e * H_DIM + h0);
  const float4* gp1 = (const float4*)(gamma + (size_t)e * H_DIM + h1);
  const float4* bp1 = (const float4*)(beta  + (size_t)e * H_DIM + h1);
  float4 ga = gp0[0], gb = gp0[1], gc = gp1[0], gd = gp1[1];
  float4 ba = bp0[0], bb = bp0[1], bc = bp1[0], bd = bp1[1];
  float gv[16] = {ga.x,ga.y,ga.z,ga.w, gb.x,gb.y,gb.z,gb.w,
                  gc.x,gc.y,gc.z,gc.w, gd.x,gd.y,gd.z,gd.w};
  float bv[16] = {ba.x,ba.y,ba.z,ba.w, bb.x,bb.y,bb.z,bb.w,
                  bc.x,bc.y,bc.z,bc.w, bd.x,bd.y,bd.z,bd.w};
#pragma unroll
  for (int j = 0; j < 8; ++j) {
    float t0 = fmaxf((v[j]     - mean) * rs * gv[j]     + bv[j],     0.f);
    float t1 = fmaxf((v[8 + j] - mean) * rs * gv[8 + j] + bv[8 + j], 0.f);
    u0[j] = f2bf(t0); u1[j] = f2bf(t1);
  }
  ((ushort8*)r)[lane] = u0; ((ushort8*)r)[lane + 64] = u1;
}

// ---------------------------------------------------------------------------
// Combine: per token, LN2 each of its 2 expert rows, y=relu(x+u), out = sum w*y
// ---------------------------------------------------------------------------
__global__ __launch_bounds__(256) void combine_kernel(
    const unsigned short* __restrict__ buf2, const float* __restrict__ X,
    const float* __restrict__ g2, const float* __restrict__ be2,
    const int* __restrict__ slots, const int* __restrict__ tk_e,
    const float* __restrict__ tk_w, float* __restrict__ out)
{
  int wid = threadIdx.x >> 6, lane = threadIdx.x & 63;
  int n = blockIdx.x * 4 + wid;
  int h0 = lane * 8, h1 = 512 + lane * 8;

  const float4* xp0 = (const float4*)(X + (size_t)n * H_DIM + h0);
  const float4* xp1 = (const float4*)(X + (size_t)n * H_DIM + h1);
  float4 xa = xp0[0], xb = xp0[1], xc = xp1[0], xd = xp1[1];
  float xv[16] = {xa.x,xa.y,xa.z,xa.w, xb.x,xb.y,xb.z,xb.w,
                  xc.x,xc.y,xc.z,xc.w, xd.x,xd.y,xd.z,xd.w};
  float o[16];
#pragma unroll
  for (int j = 0; j < 16; ++j) o[j] = 0.f;

#pragma unroll
  for (int k = 0; k < 2; ++k) {
    int slot = slots[2 * n + k];
    int e = tk_e[2 * n + k];
    float w = tk_w[2 * n + k];
    const unsigned short* r = buf2 + (size_t)slot * H_DIM;
    ushort8 u0 = ((const ushort8*)r)[lane];
    ushort8 u1 = ((const ushort8*)r)[lane + 64];
    float v[16];
#pragma unroll
    for (int j = 0; j < 8; ++j) { v[j] = bf2f(u0[j]); v[8 + j] = bf2f(u1[j]); }
    float s = 0.f, ss = 0.f;
#pragma unroll
    for (int j = 0; j < 16; ++j) { s += v[j]; ss += v[j] * v[j]; }
#pragma unroll
    for (int m = 1; m < 64; m <<= 1) { s += __shfl_xor(s, m); ss += __shfl_xor(ss, m); }
    float mean = s * (1.f / 1024.f);
    float var  = ss * (1.f / 1024.f) - mean * mean;
    float rs   = rsqrtf(var + 1e-5f);

    const float4* gp0 = (const float4*)(g2  + (size_t)e * H_DIM + h0);
    const float4* bp0 = (const float4*)(be2 + (size_t)e * H_DIM + h0);
    const float4* gp1 = (const float4*)(g2  + (size_t)e * H_DIM + h1);
    const float4* bp1 = (const float4*)(be2 + (size_t)e * H_DIM + h1);
    float4 ga = gp0[0], gb = gp0[1], gc = gp1[0], gd = gp1[1];
    float4 ba = bp0[0], bb = bp0[1], bc = bp1[0], bd = bp1[1];
    float gv[16] = {ga.x,ga.y,ga.z,ga.w, gb.x,gb.y,gb.z,gb.w,
                    gc.x,gc.y,gc.z,gc.w, gd.x,gd.y,gd.z,gd.w};
    float bvv[16] = {ba.x,ba.y,ba.z,ba.w, bb.x,bb.y,bb.z,bb.w,
                     bc.x,bc.y,bc.z,bc.w, bd.x,bd.y,bd.z,bd.w};
#pragma unroll
    for (int j = 0; j < 16; ++j) {
      float u = (v[j] - mean) * rs * gv[j] + bvv[j];
      float y = fmaxf(xv[j] + u, 0.f);
      o[j] += w * y;
    }
  }

  float4* op0 = (float4*)(out + (size_t)n * H_DIM + h0);
  float4* op1 = (float4*)(out + (size_t)n * H_DIM + h1);
  op0[0] = make_float4(o[0], o[1], o[2], o[3]);
  op0[1] = make_float4(o[4], o[5], o[6], o[7]);
  op1[0] = make_float4(o[8], o[9], o[10], o[11]);
  op1[1] = make_float4(o[12], o[13], o[14], o[15]);
}

// ---------------------------------------------------------------------------
extern "C" void kernel_launch(void* const* d_in, const int* in_sizes, int n_in,
                              void* d_out, int out_size, void* d_ws, size_t ws_size,
                              hipStream_t stream)
{
  const float* x   = (const float*)d_in[0];
  const float* Wg  = (const float*)d_in[1];
  const float* bg  = (const float*)d_in[2];
  const float* W1  = (const float*)d_in[3];
  const float* b1  = (const float*)d_in[4];
  const float* g1  = (const float*)d_in[5];
  const float* be1 = (const float*)d_in[6];
  const float* W2  = (const float*)d_in[7];
  const float* b2  = (const float*)d_in[8];
  const float* g2  = (const float*)d_in[9];
  const float* be2 = (const float*)d_in[10];
  float* out = (float*)d_out;
  float* gate_out = out + (size_t)NT * H_DIM;

  char* ws = (char*)d_ws;
  size_t off = 0;
  auto alloc = [&](size_t bytes) { char* p = ws + off; off += (bytes + 255) & ~(size_t)255; return p; };
  unsigned short* w1bt = (unsigned short*)alloc((size_t)NE * H_DIM * H_DIM * 2);
  unsigned short* w2bt = (unsigned short*)alloc((size_t)NE * H_DIM * H_DIM * 2);
  unsigned short* buf1 = (unsigned short*)alloc((size_t)NP * H_DIM * 2);
  unsigned short* buf2 = (unsigned short*)alloc((size_t)NP * H_DIM * 2);
  int*   tk_e      = (int*)alloc((size_t)NP * 4);
  float* tk_w      = (float*)alloc((size_t)NP * 4);
  int*   pairTok   = (int*)alloc((size_t)NP * 4);
  int*   pairExp   = (int*)alloc((size_t)NP * 4);
  int*   slots     = (int*)alloc((size_t)NP * 4);
  int*   blockHist = (int*)alloc(64 * 8 * 4);
  int*   blockBase = (int*)alloc(64 * 8 * 4);
  int*   count     = (int*)alloc(8 * 4);
  int*   offs      = (int*)alloc(8 * 4);
  int*   wl        = (int*)alloc(MAX_WG * 4);
  int*   wlCount   = (int*)alloc(4);
  (void)in_sizes; (void)n_in; (void)out_size; (void)ws_size;

  // Xb (bf16 copy of X) aliases buf2: consumed by gemm1 before gemm2 writes buf2.
  unsigned short* Xb = buf2;

  prep_kernel<<<dim3(8192), 256, 0, stream>>>(
      x, Wg, bg, Xb, gate_out, tk_e, tk_w, W1, W2, w1bt, w2bt);
  hist_kernel<<<dim3(64), 256, 0, stream>>>(tk_e, blockHist);
  scan_worklist_kernel<<<dim3(1), 256, 0, stream>>>(
      blockHist, blockBase, count, offs, wl, wlCount);
  place_kernel<<<dim3(64), 256, 0, stream>>>(tk_e, blockBase, pairTok, pairExp, slots);
  gemmw_kernel<true><<<dim3(MAX_WG), 256, 0, stream>>>(
      Xb, w1bt, b1, pairTok, count, offs, wl, wlCount, buf1);
  ln_relu_kernel<<<dim3(NP / 4), 256, 0, stream>>>(buf1, g1, be1, pairExp);
  gemmw_kernel<false><<<dim3(MAX_WG), 256, 0, stream>>>(
      buf1, w2bt, b2, pairTok, count, offs, wl, wlCount, buf2);
  combine_kernel<<<dim3(NT / 4), 256, 0, stream>>>(
      buf2, x, g2, be2, slots, tk_e, tk_w, out);
}

// Round 11
// 382.009 us; speedup vs baseline: 1.1265x; 1.0843x over previous
//
#include <hip/hip_runtime.h>
#include <cstdint>
#include <cstddef>

constexpr int H_DIM = 1024;
constexpr int NE    = 8;
constexpr int NT    = 16384;
constexpr int NP    = NT * 2;   // total (token, expert) pairs: exactly 2 per token

constexpr int BM = 128, BN = 128, BK = 32;
constexpr int NKT = H_DIM / BK;          // 32 K-tiles
constexpr int MAX_WG = (NP / BM + NE) * (H_DIM / BN);  // 2112

typedef __attribute__((ext_vector_type(8)))  short          short8;
typedef __attribute__((ext_vector_type(8)))  unsigned short ushort8;
typedef __attribute__((ext_vector_type(4)))  float          f32x4;

__device__ __forceinline__ unsigned short f2bf(float f) {
  union { float f; uint32_t u; } c; c.f = f;
  uint32_t u = c.u;
  u = (u + 0x7fffu + ((u >> 16) & 1u)) >> 16;   // RNE
  return (unsigned short)u;
}
__device__ __forceinline__ float bf2f(unsigned short h) {
  union { uint32_t u; float f; } c; c.u = ((uint32_t)h) << 16;
  return c.f;
}

// async 16B global -> LDS (wave-uniform LDS base; lane auto-offset *16; global addr per-lane)
__device__ __forceinline__ void gload16(const unsigned short* g, unsigned short* l) {
  __builtin_amdgcn_global_load_lds((const __attribute__((address_space(1))) void*)g,
                                   (__attribute__((address_space(3))) void*)l, 16, 0, 0);
}

// ---------------------------------------------------------------------------
// Fused prep: blocks [0,4096) = xgate (X->Xb bf16 + gating);
//             blocks [4096,8192) = W transpose-convert (fp32 [in,out] -> bf16 [out,in])
// ---------------------------------------------------------------------------
__global__ __launch_bounds__(256) void prep_kernel(
    const float* __restrict__ X, const float* __restrict__ Wg,
    const float* __restrict__ bg, unsigned short* __restrict__ Xb,
    float* __restrict__ gate_out, int* __restrict__ tk_e, float* __restrict__ tk_w,
    const float* __restrict__ W1, const float* __restrict__ W2,
    unsigned short* __restrict__ T1, unsigned short* __restrict__ T2)
{
  __shared__ float tile[64][65];
  int b = blockIdx.x;
  if (b >= 4096) {
    // ---- transpose-convert ----
    int t = b - 4096;
    int zi = t >> 8;                         // 0..15
    const float* W = (zi < 8) ? W1 : W2;
    unsigned short* T = (zi < 8) ? T1 : T2;
    int e  = zi & 7;
    int o0 = ((t >> 4) & 15) * 64;
    int h0 = (t & 15) * 64;
    int c  = threadIdx.x & 63;
    int r0 = (threadIdx.x >> 6) * 16;
    const float* src = W + ((size_t)e * H_DIM + h0) * H_DIM + o0;
#pragma unroll
    for (int i = 0; i < 16; ++i)
      tile[r0 + i][c] = src[(size_t)(r0 + i) * H_DIM + c];
    __syncthreads();
    unsigned short* dst = T + ((size_t)e * H_DIM + o0) * H_DIM + h0;
#pragma unroll
    for (int i = 0; i < 16; ++i)
      dst[(size_t)(r0 + i) * H_DIM + c] = f2bf(tile[c][r0 + i]);
    return;
  }

  // ---- xgate ----
  int wid = threadIdx.x >> 6, lane = threadIdx.x & 63;
  int n = b * 4 + wid;
  const float* xr = X + (size_t)n * H_DIM;

  const float4* xp = (const float4*)(xr + lane * 16);
  float4 f0 = xp[0], f1 = xp[1], f2 = xp[2], f3 = xp[3];
  float v[16] = {f0.x,f0.y,f0.z,f0.w, f1.x,f1.y,f1.z,f1.w,
                 f2.x,f2.y,f2.z,f2.w, f3.x,f3.y,f3.z,f3.w};

  ushort8 u0, u1;
#pragma unroll
  for (int j = 0; j < 8; ++j) { u0[j] = f2bf(v[j]); u1[j] = f2bf(v[8 + j]); }
  ushort8* xb = (ushort8*)(Xb + (size_t)n * H_DIM + lane * 16);
  xb[0] = u0; xb[1] = u1;

  float acc[8];
#pragma unroll
  for (int e = 0; e < 8; ++e) acc[e] = 0.f;
#pragma unroll
  for (int j = 0; j < 16; ++j) {
    int h = lane * 16 + j;
    const float4* wg = (const float4*)(Wg + (size_t)h * 8);
    float4 a = wg[0], bb = wg[1];
    float xv = v[j];
    acc[0] += xv * a.x;  acc[1] += xv * a.y;  acc[2] += xv * a.z;  acc[3] += xv * a.w;
    acc[4] += xv * bb.x; acc[5] += xv * bb.y; acc[6] += xv * bb.z; acc[7] += xv * bb.w;
  }
#pragma unroll
  for (int m = 1; m < 64; m <<= 1) {
#pragma unroll
    for (int e = 0; e < 8; ++e) acc[e] += __shfl_xor(acc[e], m);
  }
#pragma unroll
  for (int e = 0; e < 8; ++e) acc[e] += bg[e];

  float mx = acc[0];
#pragma unroll
  for (int e = 1; e < 8; ++e) mx = fmaxf(mx, acc[e]);
  float g[8], s = 0.f;
#pragma unroll
  for (int e = 0; e < 8; ++e) { g[e] = __expf(acc[e] - mx); s += g[e]; }
  float inv = 1.f / s;
#pragma unroll
  for (int e = 0; e < 8; ++e) g[e] *= inv;

  int e0 = 0; float b0 = g[0];
#pragma unroll
  for (int e = 1; e < 8; ++e) if (g[e] > b0) { b0 = g[e]; e0 = e; }
  int e1 = -1; float b1v = -1.f;
#pragma unroll
  for (int e = 0; e < 8; ++e) if (e != e0 && g[e] > b1v) { b1v = g[e]; e1 = e; }
  float s2 = b0 + b1v + 1e-9f;

  if (lane == 0) {
    float4* gp = (float4*)(gate_out + (size_t)n * 8);
    gp[0] = make_float4(g[0], g[1], g[2], g[3]);
    gp[1] = make_float4(g[4], g[5], g[6], g[7]);
    tk_e[2 * n] = e0; tk_e[2 * n + 1] = e1;
    tk_w[2 * n] = b0 / s2; tk_w[2 * n + 1] = b1v / s2;
  }
}

// ---------------------------------------------------------------------------
// Routing: block-hist -> scan+worklist -> block-place
// ---------------------------------------------------------------------------
__global__ __launch_bounds__(256) void hist_kernel(
    const int* __restrict__ tk_e, int* __restrict__ blockHist)
{
  __shared__ int h[8];
  if (threadIdx.x < 8) h[threadIdx.x] = 0;
  __syncthreads();
  int i0 = blockIdx.x * 512 + threadIdx.x;
  atomicAdd(&h[tk_e[i0]], 1);
  atomicAdd(&h[tk_e[i0 + 256]], 1);
  __syncthreads();
  if (threadIdx.x < 8) blockHist[blockIdx.x * 8 + threadIdx.x] = h[threadIdx.x];
}

// Worklist ordered (e, nt) outer, mt inner -> XCD chunking keeps one B col-panel
// (256 KB) L2-resident per XCD while mt-blocks stream past it.
__global__ void scan_worklist_kernel(const int* __restrict__ blockHist,
                                     int* __restrict__ blockBase,
                                     int* __restrict__ count, int* __restrict__ offs,
                                     int* __restrict__ wl, int* __restrict__ wlCount)
{
  __shared__ int nmt[8], ebase[8], totalS;
  int e = threadIdx.x;
  if (e < 8) {
    int run = 0;
    for (int b = 0; b < 64; ++b) { blockBase[b * 8 + e] = run; run += blockHist[b * 8 + e]; }
    count[e] = run;
  }
  __syncthreads();
  if (threadIdx.x == 0) {
    int o = 0, wo = 0;
    for (int k = 0; k < 8; ++k) {
      offs[k] = o; o += count[k];
      nmt[k] = (count[k] + BM - 1) / BM;
      ebase[k] = wo; wo += nmt[k] * (H_DIM / BN);
    }
    totalS = wo; wlCount[0] = wo;
  }
  __syncthreads();
  if (e < 8) {
    int o = offs[e];
    for (int b = 0; b < 64; ++b) blockBase[b * 8 + e] += o;
  }
  int total = totalS;
  for (int i = threadIdx.x; i < total; i += blockDim.x) {
    int ee = 0;
    while (ee < 7 && i >= ebase[ee + 1]) ++ee;
    int loc = i - ebase[ee];
    int nt = loc / nmt[ee];
    int mt = loc - nt * nmt[ee];
    wl[i] = (ee << 20) | (nt << 16) | mt;
  }
}

__global__ __launch_bounds__(256) void place_kernel(
    const int* __restrict__ tk_e, const int* __restrict__ blockBase,
    int* __restrict__ pairTok, int* __restrict__ pairExp, int* __restrict__ slots)
{
  __shared__ int cur[8];
  if (threadIdx.x < 8) cur[threadIdx.x] = blockBase[blockIdx.x * 8 + threadIdx.x];
  __syncthreads();
#pragma unroll
  for (int j = 0; j < 2; ++j) {
    int i = blockIdx.x * 512 + j * 256 + threadIdx.x;
    int e = tk_e[i];
    int s = atomicAdd(&cur[e], 1);
    pairTok[s] = i >> 1; pairExp[s] = e; slots[i] = s;
  }
}

// ---------------------------------------------------------------------------
// 128x128xBK32 MFMA GEMM, 4 waves (2x2 of 64x64), 16x16x32 frags, 3-slot LDS
// ring (48 KB -> 3 blocks/CU), counted vmcnt(4), one barrier per K-tile.
// st_16x32 swizzle via pre-permuted global source + XOR'd ds_read.
// R5-verified: 121 us/dispatch, 0 bank conflicts. Practical plateau of the
// 2-barrier structure family (7 structural variants R3-R10 all <= this).
// ---------------------------------------------------------------------------
template<bool GATHER>
__global__ __launch_bounds__(256, 3) void gemm3_kernel(
    const unsigned short* __restrict__ Ab,   // GATHER: Xb [NT][H]; else buf rows [NP][H]
    const unsigned short* __restrict__ Bt,   // [E][H(out)][H(in)] bf16
    const float* __restrict__ bias,          // [E][H]
    const int* __restrict__ pairTok,
    const int* __restrict__ count, const int* __restrict__ offs,
    const int* __restrict__ wl, const int* __restrict__ wlCount,
    unsigned short* __restrict__ Out)        // [NP][H] bf16
{
  __shared__ unsigned short As[3 * 4096];   // 24 KB: 3 slots x (128 rows x 32 k)
  __shared__ unsigned short Bs[3 * 4096];   // 24 KB

  const int total = wlCount[0];
  const int orig = blockIdx.x;
  if (orig >= total) return;
  // bijective XCD chunking (m204)
  const int qq = total >> 3, rr = total & 7;
  const int xcd = orig & 7, sub = orig >> 3;
  const int idx = (xcd < rr ? xcd * (qq + 1) : rr * (qq + 1) + (xcd - rr) * qq) + sub;
  const int ent = wl[idx];
  const int e = ent >> 20, ntb = (ent >> 16) & 15, mtb = ent & 0xffff;
  const int cnt = count[e], base = offs[e];

  const int tid = threadIdx.x;
  const int wid = tid >> 6, l = tid & 63;
  const int wr = wid >> 1, wc = wid & 1;

  // ---- staging source geometry (verified involution, 0 conflicts) ----
  const int rsub = (l >> 2);
  const int kswz = ((l & 3) * 8) ^ (((l >> 5) & 1) << 4);

  const unsigned short *apg0, *apg1, *bpg0, *bpg1;
  {
    int r0 = wid * 16 + rsub;          // issue 0 rows [0,64)
    int r1 = 64 + wid * 16 + rsub;     // issue 1 rows [64,128)
    int g0 = mtb * BM + r0; if (g0 >= cnt) g0 = cnt - 1;
    int g1 = mtb * BM + r1; if (g1 >= cnt) g1 = cnt - 1;
    size_t a0, a1;
    if (GATHER) { a0 = (size_t)pairTok[base + g0]; a1 = (size_t)pairTok[base + g1]; }
    else        { a0 = (size_t)(base + g0);        a1 = (size_t)(base + g1); }
    apg0 = Ab + a0 * H_DIM + kswz;
    apg1 = Ab + a1 * H_DIM + kswz;
    const unsigned short* bb = Bt + ((size_t)e * H_DIM + ntb * BN) * H_DIM + kswz;
    bpg0 = bb + (size_t)r0 * H_DIM;
    bpg1 = bb + (size_t)r1 * H_DIM;
  }

  // frag-read byte offset within 1KB subtile, same XOR involution
  const int loff = ((l & 15) * 64 + (l >> 4) * 16) ^ (((l >> 3) & 1) << 5);

  auto STAGE = [&](int u, int sl) {
    unsigned short* ad = As + sl * 4096 + wid * 512;
    unsigned short* bd = Bs + sl * 4096 + wid * 512;
    gload16(apg0 + (size_t)u * BK, ad);
    gload16(apg1 + (size_t)u * BK, ad + 2048);
    gload16(bpg0 + (size_t)u * BK, bd);
    gload16(bpg1 + (size_t)u * BK, bd + 2048);
  };

  // ---- prologue: stage tiles 0,1; ensure tile 0 done ----
  STAGE(0, 0); STAGE(1, 1);
  asm volatile("s_waitcnt vmcnt(4)" ::: "memory");
  __builtin_amdgcn_s_barrier();

  f32x4 acc[4][4] = {};

  int sl = 0, sstage = 2;
  for (int t = 0; t < NKT; ++t) {
    const char* aB = (const char*)As + sl * 8192 + wr * 4096 + loff;
    const char* bB = (const char*)Bs + sl * 8192 + wc * 4096 + loff;

    short8 af[4], bfr[4];
#pragma unroll
    for (int j = 0; j < 4; ++j) af[j] = *(const short8*)(aB + j * 1024);
#pragma unroll
    for (int r = 0; r < 4; ++r) bfr[r] = *(const short8*)(bB + r * 1024);

    if (t + 2 < NKT) STAGE(t + 2, sstage);

    __builtin_amdgcn_s_setprio(1);
#pragma unroll
    for (int j = 0; j < 4; ++j)
#pragma unroll
      for (int r = 0; r < 4; ++r)
        acc[j][r] = __builtin_amdgcn_mfma_f32_16x16x32_bf16(af[j], bfr[r], acc[j][r], 0, 0, 0);
    __builtin_amdgcn_s_setprio(0);

    if (t + 2 < NKT)       asm volatile("s_waitcnt vmcnt(4)" ::: "memory");
    else if (t + 2 == NKT) asm volatile("s_waitcnt vmcnt(0)" ::: "memory");
    __builtin_amdgcn_s_barrier();

    sl = (sl == 2) ? 0 : sl + 1;
    sstage = (sstage == 2) ? 0 : sstage + 1;
  }

  // ---- epilogue: + bias, write bf16 ----
  float bvv[4];
#pragma unroll
  for (int r = 0; r < 4; ++r)
    bvv[r] = bias[e * H_DIM + ntb * BN + wc * 64 + r * 16 + (l & 15)];
#pragma unroll
  for (int j = 0; j < 4; ++j) {
    int grow0 = mtb * BM + wr * 64 + j * 16 + (l >> 4) * 4;
#pragma unroll
    for (int r = 0; r < 4; ++r) {
      int gcol = ntb * BN + wc * 64 + r * 16 + (l & 15);
#pragma unroll
      for (int v = 0; v < 4; ++v) {
        int row = grow0 + v;
        if (row < cnt)
          Out[(size_t)(base + row) * H_DIM + gcol] = f2bf(acc[j][r][v] + bvv[r]);
      }
    }
  }
}

// ---------------------------------------------------------------------------
// In-place relu(LayerNorm(row)) on bf16 rows; one wave per row.
// ---------------------------------------------------------------------------
__global__ __launch_bounds__(256) void ln_relu_kernel(
    unsigned short* __restrict__ buf, const float* __restrict__ gamma,
    const float* __restrict__ beta, const int* __restrict__ pairExp)
{
  int wid = threadIdx.x >> 6, lane = threadIdx.x & 63;
  int row = blockIdx.x * 4 + wid;
  int e = pairExp[row];
  unsigned short* r = buf + (size_t)row * H_DIM;
  ushort8 u0 = ((const ushort8*)r)[lane];
  ushort8 u1 = ((const ushort8*)r)[lane + 64];
  float v[16];
#pragma unroll
  for (int j = 0; j < 8; ++j) { v[j] = bf2f(u0[j]); v[8 + j] = bf2f(u1[j]); }
  float s = 0.f, ss = 0.f;
#pragma unroll
  for (int j = 0; j < 16; ++j) { s += v[j]; ss += v[j] * v[j]; }
#pragma unroll
  for (int m = 1; m < 64; m <<= 1) { s += __shfl_xor(s, m); ss += __shfl_xor(ss, m); }
  float mean = s * (1.f / 1024.f);
  float var  = ss * (1.f / 1024.f) - mean * mean;
  float rs   = rsqrtf(var + 1e-5f);

  int h0 = lane * 8, h1 = 512 + lane * 8;
  const float4* gp0 = (const float4*)(gamma + (size_t)e * H_DIM + h0);
  const float4* bp0 = (const float4*)(beta  + (size_t)e * H_DIM + h0);
  const float4* gp1 = (const float4*)(gamma + (size_t)e * H_DIM + h1);
  const float4* bp1 = (const float4*)(beta  + (size_t)e * H_DIM + h1);
  float4 ga = gp0[0], gb = gp0[1], gc = gp1[0], gd = gp1[1];
  float4 ba = bp0[0], bb = bp0[1], bc = bp1[0], bd = bp1[1];
  float gv[16] = {ga.x,ga.y,ga.z,ga.w, gb.x,gb.y,gb.z,gb.w,
                  gc.x,gc.y,gc.z,gc.w, gd.x,gd.y,gd.z,gd.w};
  float bv[16] = {ba.x,ba.y,ba.z,ba.w, bb.x,bb.y,bb.z,bb.w,
                  bc.x,bc.y,bc.z,bc.w, bd.x,bd.y,bd.z,bd.w};
#pragma unroll
  for (int j = 0; j < 8; ++j) {
    float t0 = fmaxf((v[j]     - mean) * rs * gv[j]     + bv[j],     0.f);
    float t1 = fmaxf((v[8 + j] - mean) * rs * gv[8 + j] + bv[8 + j], 0.f);
    u0[j] = f2bf(t0); u1[j] = f2bf(t1);
  }
  ((ushort8*)r)[lane] = u0; ((ushort8*)r)[lane + 64] = u1;
}

// ---------------------------------------------------------------------------
// Combine: per token, LN2 each of its 2 expert rows, y=relu(x+u), out = sum w*y
// ---------------------------------------------------------------------------
__global__ __launch_bounds__(256) void combine_kernel(
    const unsigned short* __restrict__ buf2, const float* __restrict__ X,
    const float* __restrict__ g2, const float* __restrict__ be2,
    const int* __restrict__ slots, const int* __restrict__ tk_e,
    const float* __restrict__ tk_w, float* __restrict__ out)
{
  int wid = threadIdx.x >> 6, lane = threadIdx.x & 63;
  int n = blockIdx.x * 4 + wid;
  int h0 = lane * 8, h1 = 512 + lane * 8;

  const float4* xp0 = (const float4*)(X + (size_t)n * H_DIM + h0);
  const float4* xp1 = (const float4*)(X + (size_t)n * H_DIM + h1);
  float4 xa = xp0[0], xb = xp0[1], xc = xp1[0], xd = xp1[1];
  float xv[16] = {xa.x,xa.y,xa.z,xa.w, xb.x,xb.y,xb.z,xb.w,
                  xc.x,xc.y,xc.z,xc.w, xd.x,xd.y,xd.z,xd.w};
  float o[16];
#pragma unroll
  for (int j = 0; j < 16; ++j) o[j] = 0.f;

#pragma unroll
  for (int k = 0; k < 2; ++k) {
    int slot = slots[2 * n + k];
    int e = tk_e[2 * n + k];
    float w = tk_w[2 * n + k];
    const unsigned short* r = buf2 + (size_t)slot * H_DIM;
    ushort8 u0 = ((const ushort8*)r)[lane];
    ushort8 u1 = ((const ushort8*)r)[lane + 64];
    float v[16];
#pragma unroll
    for (int j = 0; j < 8; ++j) { v[j] = bf2f(u0[j]); v[8 + j] = bf2f(u1[j]); }
    float s = 0.f, ss = 0.f;
#pragma unroll
    for (int j = 0; j < 16; ++j) { s += v[j]; ss += v[j] * v[j]; }
#pragma unroll
    for (int m = 1; m < 64; m <<= 1) { s += __shfl_xor(s, m); ss += __shfl_xor(ss, m); }
    float mean = s * (1.f / 1024.f);
    float var  = ss * (1.f / 1024.f) - mean * mean;
    float rs   = rsqrtf(var + 1e-5f);

    const float4* gp0 = (const float4*)(g2  + (size_t)e * H_DIM + h0);
    const float4* bp0 = (const float4*)(be2 + (size_t)e * H_DIM + h0);
    const float4* gp1 = (const float4*)(g2  + (size_t)e * H_DIM + h1);
    const float4* bp1 = (const float4*)(be2 + (size_t)e * H_DIM + h1);
    float4 ga = gp0[0], gb = gp0[1], gc = gp1[0], gd = gp1[1];
    float4 ba = bp0[0], bb = bp0[1], bc = bp1[0], bd = bp1[1];
    float gv[16] = {ga.x,ga.y,ga.z,ga.w, gb.x,gb.y,gb.z,gb.w,
                    gc.x,gc.y,gc.z,gc.w, gd.x,gd.y,gd.z,gd.w};
    float bvv[16] = {ba.x,ba.y,ba.z,ba.w, bb.x,bb.y,bb.z,bb.w,
                     bc.x,bc.y,bc.z,bc.w, bd.x,bd.y,bd.z,bd.w};
#pragma unroll
    for (int j = 0; j < 16; ++j) {
      float u = (v[j] - mean) * rs * gv[j] + bvv[j];
      float y = fmaxf(xv[j] + u, 0.f);
      o[j] += w * y;
    }
  }

  float4* op0 = (float4*)(out + (size_t)n * H_DIM + h0);
  float4* op1 = (float4*)(out + (size_t)n * H_DIM + h1);
  op0[0] = make_float4(o[0], o[1], o[2], o[3]);
  op0[1] = make_float4(o[4], o[5], o[6], o[7]);
  op1[0] = make_float4(o[8], o[9], o[10], o[11]);
  op1[1] = make_float4(o[12], o[13], o[14], o[15]);
}

// ---------------------------------------------------------------------------
extern "C" void kernel_launch(void* const* d_in, const int* in_sizes, int n_in,
                              void* d_out, int out_size, void* d_ws, size_t ws_size,
                              hipStream_t stream)
{
  const float* x   = (const float*)d_in[0];
  const float* Wg  = (const float*)d_in[1];
  const float* bg  = (const float*)d_in[2];
  const float* W1  = (const float*)d_in[3];
  const float* b1  = (const float*)d_in[4];
  const float* g1  = (const float*)d_in[5];
  const float* be1 = (const float*)d_in[6];
  const float* W2  = (const float*)d_in[7];
  const float* b2  = (const float*)d_in[8];
  const float* g2  = (const float*)d_in[9];
  const float* be2 = (const float*)d_in[10];
  float* out = (float*)d_out;
  float* gate_out = out + (size_t)NT * H_DIM;

  char* ws = (char*)d_ws;
  size_t off = 0;
  auto alloc = [&](size_t bytes) { char* p = ws + off; off += (bytes + 255) & ~(size_t)255; return p; };
  unsigned short* w1bt = (unsigned short*)alloc((size_t)NE * H_DIM * H_DIM * 2);
  unsigned short* w2bt = (unsigned short*)alloc((size_t)NE * H_DIM * H_DIM * 2);
  unsigned short* buf1 = (unsigned short*)alloc((size_t)NP * H_DIM * 2);
  unsigned short* buf2 = (unsigned short*)alloc((size_t)NP * H_DIM * 2);
  int*   tk_e      = (int*)alloc((size_t)NP * 4);
  float* tk_w      = (float*)alloc((size_t)NP * 4);
  int*   pairTok   = (int*)alloc((size_t)NP * 4);
  int*   pairExp   = (int*)alloc((size_t)NP * 4);
  int*   slots     = (int*)alloc((size_t)NP * 4);
  int*   blockHist = (int*)alloc(64 * 8 * 4);
  int*   blockBase = (int*)alloc(64 * 8 * 4);
  int*   count     = (int*)alloc(8 * 4);
  int*   offs      = (int*)alloc(8 * 4);
  int*   wl        = (int*)alloc(MAX_WG * 4);
  int*   wlCount   = (int*)alloc(4);
  (void)in_sizes; (void)n_in; (void)out_size; (void)ws_size;

  // Xb (bf16 copy of X) aliases buf2: consumed by gemm1 before gemm2 writes buf2.
  unsigned short* Xb = buf2;

  prep_kernel<<<dim3(8192), 256, 0, stream>>>(
      x, Wg, bg, Xb, gate_out, tk_e, tk_w, W1, W2, w1bt, w2bt);
  hist_kernel<<<dim3(64), 256, 0, stream>>>(tk_e, blockHist);
  scan_worklist_kernel<<<dim3(1), 256, 0, stream>>>(
      blockHist, blockBase, count, offs, wl, wlCount);
  place_kernel<<<dim3(64), 256, 0, stream>>>(tk_e, blockBase, pairTok, pairExp, slots);
  gemm3_kernel<true><<<dim3(MAX_WG), 256, 0, stream>>>(
      Xb, w1bt, b1, pairTok, count, offs, wl, wlCount, buf1);
  ln_relu_kernel<<<dim3(NP / 4), 256, 0, stream>>>(buf1, g1, be1, pairExp);
  gemm3_kernel<false><<<dim3(MAX_WG), 256, 0, stream>>>(
      buf1, w2bt, b2, pairTok, count, offs, wl, wlCount, buf2);
  combine_kernel<<<dim3(NT / 4), 256, 0, stream>>>(
      buf2, x, g2, be2, slots, tk_e, tk_w, out);
}